// Round 1
// baseline (204.152 us; speedup 1.0000x reference)
//
#include <hip/hip_runtime.h>

typedef unsigned short u16t;
typedef __bf16 bf16x8 __attribute__((ext_vector_type(8)));
typedef float  f32x4  __attribute__((ext_vector_type(4)));

#define SLOPE 0.01f
#define SAP 136   // LDS pitch (u16) for 128-col rows: 272 B, 16B-aligned, P/16 odd
#define UIP 72    // LDS pitch (u16) for 64-col ui rows: 144 B, 16B-aligned
#define CPB 4     // chunks (64 rows each) per block in ao_main

__device__ __forceinline__ float lrelu(float x) { return x >= 0.0f ? x : SLOPE * x; }
__device__ __forceinline__ u16t f2b(float f) {
    union { float f; unsigned i; } x; x.f = f;
    return (u16t)((x.i + 0x7fffu + ((x.i >> 16) & 1u)) >> 16);
}
__device__ __forceinline__ float b2f(u16t u) {
    union { unsigned i; float f; } x; x.i = ((unsigned)u) << 16; return x.f;
}
// gfx950 HW packed f32->bf16 (RNE): dst.lo = bf16(a), dst.hi = bf16(b)
__device__ __forceinline__ unsigned pk2(float a, float b) {
    unsigned r;
    asm("v_cvt_pk_bf16_f32 %0, %1, %2" : "=v"(r) : "v"(a), "v"(b));
    return r;
}
__device__ __forceinline__ uint4 pack8(float4 x, float4 y) {
    uint4 r; r.x = pk2(x.x, x.y); r.y = pk2(x.z, x.w);
    r.z = pk2(y.x, y.y); r.w = pk2(y.z, y.w); return r;
}
__device__ __forceinline__ int clmp3(int v) { return v < 0 ? 0 : (v > 2 ? 2 : v); }

// Raw barrier WITHOUT the __syncthreads vmcnt(0) drain: keeps the register
// prefetch loads in flight across phase boundaries (T14). Writer-side LDS
// drain (lgkmcnt) before the barrier; memory clobbers pin ordering.
__device__ __forceinline__ void block_sync() {
    asm volatile("s_waitcnt lgkmcnt(0)" ::: "memory");
    __builtin_amdgcn_s_barrier();
    asm volatile("" ::: "memory");
}

// ---------------------------------------------------------------------------
// Kernel A = pack_w (blocks 0..383) + passA histograms (blocks 384..639).
// ---------------------------------------------------------------------------
__global__ __launch_bounds__(256) void kernelA(
    const float* __restrict__ W0, const float* __restrict__ W1,
    const float* __restrict__ uW0, const float* __restrict__ uW1,
    const int* __restrict__ s,
    u16t* __restrict__ W0p, u16t* __restrict__ W1p,
    u16t* __restrict__ U0p, u16t* __restrict__ U1p,
    int* __restrict__ cntB)
{
    __shared__ int sc[3];
    const int t = threadIdx.x;
    if (blockIdx.x < 384) {
        int tid = blockIdx.x * 256 + t;
        if (tid < 49152) {                       // W0p [3][4][8][64][8]
            int j = tid & 7, lane = (tid >> 3) & 63, c = (tid >> 9) & 7,
                kk = (tid >> 12) & 3, r = tid >> 14;
            int k = kk * 32 + (lane >> 4) * 8 + j, n = c * 16 + (lane & 15);
            W0p[tid] = f2b(W0[(r * 128 + k) * 128 + n]);
        } else if (tid < 73728) {                // W1p [3][4][4][64][8]
            int t2 = tid - 49152;
            int j = t2 & 7, lane = (t2 >> 3) & 63, c = (t2 >> 9) & 3,
                kk = (t2 >> 11) & 3, r = t2 >> 13;
            int k = kk * 32 + (lane >> 4) * 8 + j, n = c * 16 + (lane & 15);
            W1p[t2] = f2b(W1[(r * 128 + k) * 64 + n]);
        } else if (tid < 90112) {                // U0p [4][8][64][8]
            int t3 = tid - 73728;
            int j = t3 & 7, lane = (t3 >> 3) & 63, c = (t3 >> 9) & 7, kk = t3 >> 12;
            int k = kk * 32 + (lane >> 4) * 8 + j, n = c * 16 + (lane & 15);
            U0p[t3] = f2b(uW0[k * 128 + n]);
        } else if (tid < 98304) {                // U1p [4][4][64][8]
            int t4 = tid - 90112;
            int j = t4 & 7, lane = (t4 >> 3) & 63, c = (t4 >> 9) & 3, kk = t4 >> 11;
            int k = kk * 32 + (lane >> 4) * 8 + j, n = c * 16 + (lane & 15);
            U1p[t4] = f2b(uW1[k * 64 + n]);
        }
    } else {
        const int blk = blockIdx.x - 384;
        if (t < 3) sc[t] = 0;
        __syncthreads();
        int4 sv = ((const int4*)s)[blk * 256 + t];
        int l0 = 0, l1 = 0, l2 = 0, r;
        r = clmp3(sv.x); l0 += (r == 0); l1 += (r == 1); l2 += (r == 2);
        r = clmp3(sv.y); l0 += (r == 0); l1 += (r == 1); l2 += (r == 2);
        r = clmp3(sv.z); l0 += (r == 0); l1 += (r == 1); l2 += (r == 2);
        r = clmp3(sv.w); l0 += (r == 0); l1 += (r == 1); l2 += (r == 2);
        atomicAdd(&sc[0], l0); atomicAdd(&sc[1], l1); atomicAdd(&sc[2], l2);
        __syncthreads();
        if (t < 3) cntB[blk * 3 + t] = sc[t];
    }
}

// ---------------------------------------------------------------------------
// Kernel B = prep_ui (blocks 0..255, 512 thr) + passB scan/scatter
// (blocks 256..511, first 256 thr active, barriers by all).
// ---------------------------------------------------------------------------
__global__ __launch_bounds__(512) void kernelB(
    const float* __restrict__ u_emb, const float* __restrict__ i_emb,
    const u16t* __restrict__ U0p, const u16t* __restrict__ U1p,
    const float* __restrict__ uib0, const float* __restrict__ uib1,
    const int* __restrict__ s, const int* __restrict__ cntB,
    u16t* __restrict__ uiT, int* __restrict__ cntOut, int* __restrict__ rows)
{
    __shared__ __align__(16) u16t sA[32 * SAP];
    __shared__ __align__(16) u16t sH[32 * SAP];
    __shared__ int sTab[768];
    __shared__ int sBT[6];
    __shared__ int sS[256];
    const int t = threadIdx.x;

    if (blockIdx.x < 256) {
        // ---------------- prep_ui ----------------
        const int wave = t >> 6, lane = t & 63, m = lane & 15, kg = lane >> 4;
        const int c = wave, c2 = wave & 3, hlf = wave >> 2;
        const int B0 = blockIdx.x * 32;

        bf16x8 w0f[4], w1f[4];
#pragma unroll
        for (int kk = 0; kk < 4; ++kk) {
            w0f[kk] = *(const bf16x8*)(U0p + (((kk * 8 + c) * 64 + lane) << 3));
            w1f[kk] = *(const bf16x8*)(U1p + (((kk * 4 + c2) * 64 + lane) << 3));
        }
        const float b0 = uib0[c * 16 + m], b1 = uib1[c2 * 16 + m];

        {   // stage 32 rows of u||i (f32 -> bf16)
            const int row = t >> 4, seg = t & 15;
            const float* src = (seg < 8) ? (u_emb + (size_t)(B0 + row) * 64 + seg * 8)
                                         : (i_emb + (size_t)(B0 + row) * 64 + (seg - 8) * 8);
            float4 v0 = ((const float4*)src)[0], v1 = ((const float4*)src)[1];
            *(uint4*)&sA[row * SAP + seg * 8] = pack8(v0, v1);
        }
        __syncthreads();

#pragma unroll
        for (int mt = 0; mt < 2; ++mt) {
            const u16t* ap = &sA[(mt * 16 + m) * SAP + kg * 8];
            bf16x8 a0 = *(const bf16x8*)(ap),      a1 = *(const bf16x8*)(ap + 32);
            bf16x8 a2 = *(const bf16x8*)(ap + 64), a3 = *(const bf16x8*)(ap + 96);
            f32x4 acc = {0.f, 0.f, 0.f, 0.f};
            acc = __builtin_amdgcn_mfma_f32_16x16x32_bf16(a0, w0f[0], acc, 0, 0, 0);
            acc = __builtin_amdgcn_mfma_f32_16x16x32_bf16(a1, w0f[1], acc, 0, 0, 0);
            acc = __builtin_amdgcn_mfma_f32_16x16x32_bf16(a2, w0f[2], acc, 0, 0, 0);
            acc = __builtin_amdgcn_mfma_f32_16x16x32_bf16(a3, w0f[3], acc, 0, 0, 0);
#pragma unroll
            for (int j = 0; j < 4; ++j)
                sH[(mt * 16 + kg * 4 + j) * SAP + c * 16 + m] = f2b(lrelu(acc[j] + b0));
        }
        __syncthreads();

        {   // L1: wave (hlf,c2) handles tile mt=hlf
            const int mt = hlf;
            const u16t* hp = &sH[(mt * 16 + m) * SAP + kg * 8];
            bf16x8 a0 = *(const bf16x8*)(hp),      a1 = *(const bf16x8*)(hp + 32);
            bf16x8 a2 = *(const bf16x8*)(hp + 64), a3 = *(const bf16x8*)(hp + 96);
            f32x4 acc = {0.f, 0.f, 0.f, 0.f};
            acc = __builtin_amdgcn_mfma_f32_16x16x32_bf16(a0, w1f[0], acc, 0, 0, 0);
            acc = __builtin_amdgcn_mfma_f32_16x16x32_bf16(a1, w1f[1], acc, 0, 0, 0);
            acc = __builtin_amdgcn_mfma_f32_16x16x32_bf16(a2, w1f[2], acc, 0, 0, 0);
            acc = __builtin_amdgcn_mfma_f32_16x16x32_bf16(a3, w1f[3], acc, 0, 0, 0);
#pragma unroll
            for (int j = 0; j < 4; ++j)
                uiT[(size_t)(B0 + mt * 16 + kg * 4 + j) * 64 + c2 * 16 + m] =
                    f2b(lrelu(acc[j] + b1));
        }
    } else {
        // ---------------- passB ----------------
        const int blk = blockIdx.x - 256;
        if (t < 256) {
            sTab[t] = cntB[t]; sTab[t + 256] = cntB[t + 256]; sTab[t + 512] = cntB[t + 512];
        }
        __syncthreads();
        if (t < 3) {
            int base = 0, tot = 0;
            for (int b = 0; b < 256; ++b) {
                int v = sTab[b * 3 + t];
                if (b < blk) base += v;
                tot += v;
            }
            sBT[t] = base; sBT[3 + t] = tot;
        }
        int rr0 = 0, rr1 = 0, rr2 = 0, rr3 = 0, packed = 0;
        if (t < 256) {
            int4 sv = ((const int4*)s)[blk * 256 + t];
            rr0 = clmp3(sv.x); rr1 = clmp3(sv.y); rr2 = clmp3(sv.z); rr3 = clmp3(sv.w);
            packed = (1 << (11 * rr0)) + (1 << (11 * rr1))
                   + (1 << (11 * rr2)) + (1 << (11 * rr3));
            sS[t] = packed;
        }
        __syncthreads();
        for (int off = 1; off < 256; off <<= 1) {
            int v = 0;
            if (t >= off && t < 256) v = sS[t - off];
            __syncthreads();
            if (t < 256) sS[t] += v;
            __syncthreads();
        }
        if (t < 256) {
            const int excl = sS[t] - packed;
            const int g1 = sBT[3], g2 = sBT[3] + sBT[4];
            int rr[4] = { rr0, rr1, rr2, rr3 };
            int seen[3] = {0, 0, 0};
#pragma unroll
            for (int i = 0; i < 4; ++i) {
                int rl = rr[i];
                int gb = rl == 0 ? 0 : (rl == 1 ? g1 : g2);
                int pos = gb + sBT[rl] + ((excl >> (11 * rl)) & 2047) + seen[rl];
                seen[rl]++;
                rows[pos] = blk * 1024 + t * 4 + i;
            }
        }
        if (blk == 0 && t < 3) cntOut[t] = sBT[3 + t];
    }
}

// ---------------------------------------------------------------------------
// AO main v2: software-pipelined. CPB=4 chunks of 64 rows per block; per chunk
// 2 phases / 2 raw barriers:
//   Phase A: issue chunk+1 globals -> regs, issue rows idx chunk+2,
//            store chunk-1 pred, zero sPred[par], L0 MFMAs (sA -> sH).
//   Phase B: L1 MFMAs + dot + LDS-atomic pred; then vmcnt-wait + ds_write
//            chunk+1 into sA (single buf, last read was Phase A) and
//            sUIl[par^1] (double buffered).
// Raw s_barrier + lgkmcnt(0) drain keeps prefetch loads in flight (T14).
// ---------------------------------------------------------------------------
__device__ __forceinline__ void chunk_info(int chunk, int ch0, int ch01,
                                           int n0, int n1, int n2,
                                           int& r, int& bb, int& rstart, int& nrows)
{
    int rel, nb;
    if (chunk < ch0)       { r = 0; rel = chunk;        bb = 0;       nb = n0; }
    else if (chunk < ch01) { r = 1; rel = chunk - ch0;  bb = n0;      nb = n1; }
    else                   { r = 2; rel = chunk - ch01; bb = n0 + n1; nb = n2; }
    rstart = rel * 64;
    int nr = nb - rstart; nrows = nr > 64 ? 64 : nr;
}

__global__ __launch_bounds__(512, 4) void ao_main(
    const float* __restrict__ a_emb, const float* __restrict__ o_emb,
    const float* __restrict__ ao_b0, const float* __restrict__ ao_b1,
    const u16t* __restrict__ W0p, const u16t* __restrict__ W1p,
    const u16t* __restrict__ uiT, const int* __restrict__ rows,
    const int* __restrict__ tot, float* __restrict__ out)
{
    __shared__ __align__(16) u16t sA[64 * SAP];          // 17408 B
    __shared__ __align__(16) u16t sH[64 * SAP];          // 17408 B
    __shared__ __align__(16) u16t sUIl[2][64 * UIP];     // 18432 B
    __shared__ float sPred[2][64];                       //   512 B

    const int n0 = tot[0], n1 = tot[1], n2 = tot[2];
    const int ch0 = (n0 + 63) >> 6, ch1 = (n1 + 63) >> 6, ch2 = (n2 + 63) >> 6;
    const int ch01 = ch0 + ch1;
    const int nch = ch01 + ch2;
    const int chunk0 = blockIdx.x * CPB;
    if (chunk0 >= nch) return;

    const int t = threadIdx.x, wave = t >> 6, lane = t & 63, m = lane & 15, kg = lane >> 4;
    const int c = wave, c2 = wave & 3, hlf = wave >> 2;
    const int q = t >> 3, seg = t & 7;      // staging role: row q, 64B segment seg

    bf16x8 w0f[4], w1f[4];
    float b0 = 0.f, b1 = 0.f;
    int rprev = -1;

    // ---- prologue: gather chunk0 -> regs -> LDS; prefetch idx for chunk1 ----
    int r0, bb0, rs0, nr0;
    chunk_info(chunk0, ch0, ch01, n0, n1, n2, r0, bb0, rs0, nr0);
    int ridCur = rows[bb0 + rs0 + (q < nr0 ? q : nr0 - 1)];

    float4 pv0, pv1, pv2, pv3; uint4 puv;
    {
        const float* src = (seg < 4) ? (a_emb + (size_t)ridCur * 64 + seg * 16)
                                     : (o_emb + (size_t)ridCur * 64 + (seg - 4) * 16);
        pv0 = ((const float4*)src)[0]; pv1 = ((const float4*)src)[1];
        pv2 = ((const float4*)src)[2]; pv3 = ((const float4*)src)[3];
        puv = *(const uint4*)(uiT + ((size_t)(ridCur >> 5)) * 64 + seg * 8);
    }
    int ridNext = 0;
    if (CPB > 1 && chunk0 + 1 < nch) {
        int r1, bb1, rs1, nr1;
        chunk_info(chunk0 + 1, ch0, ch01, n0, n1, n2, r1, bb1, rs1, nr1);
        ridNext = rows[bb1 + rs1 + (q < nr1 ? q : nr1 - 1)];
    }
    {
        uint4* dst = (uint4*)&sA[q * SAP + seg * 16];
        dst[0] = pack8(pv0, pv1); dst[1] = pack8(pv2, pv3);
        *(uint4*)&sUIl[0][q * UIP + seg * 8] = puv;
    }
    int ridPrev = 0, nrowsPrev = 0, lastPar = 0;
    block_sync();

    for (int ci = 0; ci < CPB; ++ci) {
        const int chunk = chunk0 + ci;
        if (chunk >= nch) break;                        // block-uniform
        int r, bb, rstart, nrows;
        chunk_info(chunk, ch0, ch01, n0, n1, n2, r, bb, rstart, nrows);

        if (r != rprev) {            // block-uniform; rare (sorted chunks)
            const u16t* wp0 = W0p + r * 16384;
            const u16t* wp1 = W1p + r * 8192;
#pragma unroll
            for (int kk = 0; kk < 4; ++kk) {
                w0f[kk] = *(const bf16x8*)(wp0 + (((kk * 8 + c) * 64 + lane) << 3));
                w1f[kk] = *(const bf16x8*)(wp1 + (((kk * 4 + c2) * 64 + lane) << 3));
            }
            b0 = ao_b0[r * 128 + c * 16 + m];
            b1 = ao_b1[r * 64 + c2 * 16 + m];
            rprev = r;
        }

        // ================= Phase A =================
        const bool valid1 = (ci + 1 < CPB) && (chunk + 1 < nch);
        const bool valid2 = (ci + 2 < CPB) && (chunk + 2 < nch);
        if (valid1) {   // issue chunk+1 data loads -> regs (consumed Phase B end)
            const float* src = (seg < 4) ? (a_emb + (size_t)ridNext * 64 + seg * 16)
                                         : (o_emb + (size_t)ridNext * 64 + (seg - 4) * 16);
            pv0 = ((const float4*)src)[0]; pv1 = ((const float4*)src)[1];
            pv2 = ((const float4*)src)[2]; pv3 = ((const float4*)src)[3];
            puv = *(const uint4*)(uiT + ((size_t)(ridNext >> 5)) * 64 + seg * 8);
        }
        int ridNext2 = 0;
        if (valid2) {   // issue chunk+2 index load (consumed next Phase A)
            int r2, bb2, rs2, nr2;
            chunk_info(chunk + 2, ch0, ch01, n0, n1, n2, r2, bb2, rs2, nr2);
            ridNext2 = rows[bb2 + rs2 + (q < nr2 ? q : nr2 - 1)];
        }
        if (ci > 0 && seg == 0 && q < nrowsPrev)        // store chunk-1 pred
            out[ridPrev] = sPred[(ci - 1) & 1][q];
        if (t < 64) sPred[ci & 1][t] = 0.0f;

        // L0: h0 = lrelu(ao_in @ W0[r] + b0) -> sH
#pragma unroll
        for (int mt = 0; mt < 4; ++mt) {
            const u16t* ap = &sA[(mt * 16 + m) * SAP + kg * 8];
            bf16x8 a0 = *(const bf16x8*)(ap),      a1 = *(const bf16x8*)(ap + 32);
            bf16x8 a2 = *(const bf16x8*)(ap + 64), a3 = *(const bf16x8*)(ap + 96);
            f32x4 acc_a = {0.f, 0.f, 0.f, 0.f}, acc_b = {0.f, 0.f, 0.f, 0.f};
            acc_a = __builtin_amdgcn_mfma_f32_16x16x32_bf16(a0, w0f[0], acc_a, 0, 0, 0);
            acc_a = __builtin_amdgcn_mfma_f32_16x16x32_bf16(a1, w0f[1], acc_a, 0, 0, 0);
            acc_b = __builtin_amdgcn_mfma_f32_16x16x32_bf16(a2, w0f[2], acc_b, 0, 0, 0);
            acc_b = __builtin_amdgcn_mfma_f32_16x16x32_bf16(a3, w0f[3], acc_b, 0, 0, 0);
            f32x4 acc = acc_a + acc_b;
            unsigned pA = pk2(lrelu(acc[0] + b0), lrelu(acc[1] + b0));
            unsigned pB = pk2(lrelu(acc[2] + b0), lrelu(acc[3] + b0));
            u16t* hp = &sH[(mt * 16 + kg * 4) * SAP + c * 16 + m];
            hp[0]       = (u16t)pA;
            hp[SAP]     = (u16t)(pA >> 16);
            hp[2 * SAP] = (u16t)pB;
            hp[3 * SAP] = (u16t)(pB >> 16);
        }
        block_sync();

        // ================= Phase B =================
        const int par = ci & 1;
        for (int mt = hlf; mt < 4; mt += 2) {
            const u16t* hp2 = &sH[(mt * 16 + m) * SAP + kg * 8];
            bf16x8 a0 = *(const bf16x8*)(hp2),      a1 = *(const bf16x8*)(hp2 + 32);
            bf16x8 a2 = *(const bf16x8*)(hp2 + 64), a3 = *(const bf16x8*)(hp2 + 96);
            f32x4 acc_a = {0.f, 0.f, 0.f, 0.f}, acc_b = {0.f, 0.f, 0.f, 0.f};
            acc_a = __builtin_amdgcn_mfma_f32_16x16x32_bf16(a0, w1f[0], acc_a, 0, 0, 0);
            acc_a = __builtin_amdgcn_mfma_f32_16x16x32_bf16(a1, w1f[1], acc_a, 0, 0, 0);
            acc_b = __builtin_amdgcn_mfma_f32_16x16x32_bf16(a2, w1f[2], acc_b, 0, 0, 0);
            acc_b = __builtin_amdgcn_mfma_f32_16x16x32_bf16(a3, w1f[3], acc_b, 0, 0, 0);
            f32x4 acc = acc_a + acc_b;
            const int o = c2 * 16 + m;
            float pj[4];
#pragma unroll
            for (int j = 0; j < 4; ++j) {
                const int rq = mt * 16 + kg * 4 + j;
                pj[j] = lrelu(acc[j] + b1) * b2f(sUIl[par][rq * UIP + o]);
            }
#pragma unroll
            for (int msk = 8; msk >= 1; msk >>= 1) {
#pragma unroll
                for (int j = 0; j < 4; ++j) pj[j] += __shfl_xor(pj[j], msk, 16);
            }
            if (m == 0) {
#pragma unroll
                for (int j = 0; j < 4; ++j)
                    atomicAdd(&sPred[par][mt * 16 + kg * 4 + j], pj[j]);
            }
        }
        if (valid1) {   // vmcnt-wait on pv (compiler-inserted) + stage chunk+1
            uint4* dst = (uint4*)&sA[q * SAP + seg * 16];
            dst[0] = pack8(pv0, pv1); dst[1] = pack8(pv2, pv3);
            *(uint4*)&sUIl[par ^ 1][q * UIP + seg * 8] = puv;
        }
        ridPrev = ridCur; nrowsPrev = nrows; ridCur = ridNext; ridNext = ridNext2;
        lastPar = par;
        block_sync();
    }

    // epilogue: store the last processed chunk's pred
    if (seg == 0 && q < nrowsPrev)
        out[ridPrev] = sPred[lastPar][q];
}

extern "C" void kernel_launch(void* const* d_in, const int* in_sizes, int n_in,
                              void* d_out, int out_size, void* d_ws, size_t ws_size,
                              hipStream_t stream) {
    (void)in_sizes; (void)n_in; (void)out_size; (void)ws_size;
    const float* u_emb = (const float*)d_in[0];
    const float* i_emb = (const float*)d_in[1];
    const float* a_emb = (const float*)d_in[2];
    const float* o_emb = (const float*)d_in[3];
    const int*   s     = (const int*)  d_in[4];
    const float* aoW0  = (const float*)d_in[5];
    const float* aob0  = (const float*)d_in[6];
    const float* aoW1  = (const float*)d_in[7];
    const float* aob1  = (const float*)d_in[8];
    const float* uiW0  = (const float*)d_in[9];
    const float* uib0  = (const float*)d_in[10];
    const float* uiW1  = (const float*)d_in[11];
    const float* uib1  = (const float*)d_in[12];
    float* out = (float*)d_out;

    char* ws = (char*)d_ws;
    u16t* W0p  = (u16t*)(ws);                 //  98304 B
    u16t* W1p  = (u16t*)(ws + 98304);         //  49152 B
    u16t* U0p  = (u16t*)(ws + 147456);        //  32768 B
    u16t* U1p  = (u16t*)(ws + 180224);        //  16384 B
    u16t* uiT  = (u16t*)(ws + 196608);        // 1048576 B (8192*64 bf16)
    int*  cntB = (int*) (ws + 1245184);       //   3072 B
    int*  totC = (int*) (ws + 1248256);       //     16 B
    int*  rowsP= (int*) (ws + 1248272);       // 1048576 B (262144 int)

    kernelA<<<dim3(640), dim3(256), 0, stream>>>(
        aoW0, aoW1, uiW0, uiW1, s, W0p, W1p, U0p, U1p, cntB);
    kernelB<<<dim3(512), dim3(512), 0, stream>>>(
        u_emb, i_emb, U0p, U1p, uib0, uib1, s, cntB, uiT, totC, rowsP);
    // CPB=4 chunks/block; nch <= ceil(262144/64)+2 = 4098 -> 1025 blocks
    ao_main<<<dim3(1025), dim3(512), 0, stream>>>(
        a_emb, o_emb, aob0, aob1, W0p, W1p, uiT, rowsP, totC, out);
}

// Round 2
// 196.585 us; speedup vs baseline: 1.0385x; 1.0385x over previous
//
#include <hip/hip_runtime.h>

typedef unsigned short u16t;
typedef __bf16 bf16x8 __attribute__((ext_vector_type(8)));
typedef float  f32x4  __attribute__((ext_vector_type(4)));

#define SLOPE 0.01f
#define SAP 136   // LDS pitch (u16) for 128-col rows: 272 B, 16B-aligned
#define UIP 72    // LDS pitch (u16) for 64-col ui rows: 144 B, 16B-aligned

__device__ __forceinline__ float lrelu(float x) { return x >= 0.0f ? x : SLOPE * x; }
__device__ __forceinline__ u16t f2b(float f) {
    union { float f; unsigned i; } x; x.f = f;
    return (u16t)((x.i + 0x7fffu + ((x.i >> 16) & 1u)) >> 16);
}
__device__ __forceinline__ float b2f(u16t u) {
    union { unsigned i; float f; } x; x.i = ((unsigned)u) << 16; return x.f;
}
// gfx950 HW packed f32->bf16 (RNE): dst.lo = bf16(a), dst.hi = bf16(b)
__device__ __forceinline__ unsigned pk2(float a, float b) {
    unsigned r;
    asm("v_cvt_pk_bf16_f32 %0, %1, %2" : "=v"(r) : "v"(a), "v"(b));
    return r;
}
__device__ __forceinline__ uint4 pack8(float4 x, float4 y) {
    uint4 r; r.x = pk2(x.x, x.y); r.y = pk2(x.z, x.w);
    r.z = pk2(y.x, y.y); r.w = pk2(y.z, y.w); return r;
}
__device__ __forceinline__ int clmp3(int v) { return v < 0 ? 0 : (v > 2 ? 2 : v); }

// Reduce across a 16-lane DPP row via rotate-accumulate: pure VALU (no LDS
// pipe, unlike __shfl_xor's ds_swizzle). After ror 8,4,2,1 every lane of the
// row holds the full 16-lane sum.
template <int CTRL>
__device__ __forceinline__ float dpp_ror_add(float x) {
    union { float f; int i; } a, b;
    a.f = x;
    b.i = __builtin_amdgcn_update_dpp(0, a.i, CTRL, 0xF, 0xF, true);
    return x + b.f;
}
__device__ __forceinline__ float row16_sum(float x) {
    x = dpp_ror_add<0x128>(x);   // row_ror:8
    x = dpp_ror_add<0x124>(x);   // row_ror:4
    x = dpp_ror_add<0x122>(x);   // row_ror:2
    x = dpp_ror_add<0x121>(x);   // row_ror:1
    return x;
}

// ---------------------------------------------------------------------------
// Kernel A = pack_w (blocks 0..383) + passA histograms (blocks 384..639).
// ---------------------------------------------------------------------------
__global__ __launch_bounds__(256) void kernelA(
    const float* __restrict__ W0, const float* __restrict__ W1,
    const float* __restrict__ uW0, const float* __restrict__ uW1,
    const int* __restrict__ s,
    u16t* __restrict__ W0p, u16t* __restrict__ W1p,
    u16t* __restrict__ U0p, u16t* __restrict__ U1p,
    int* __restrict__ cntB)
{
    __shared__ int sc[3];
    const int t = threadIdx.x;
    if (blockIdx.x < 384) {
        int tid = blockIdx.x * 256 + t;
        if (tid < 49152) {                       // W0p [3][4][8][64][8]
            int j = tid & 7, lane = (tid >> 3) & 63, c = (tid >> 9) & 7,
                kk = (tid >> 12) & 3, r = tid >> 14;
            int k = kk * 32 + (lane >> 4) * 8 + j, n = c * 16 + (lane & 15);
            W0p[tid] = f2b(W0[(r * 128 + k) * 128 + n]);
        } else if (tid < 73728) {                // W1p [3][4][4][64][8]
            int t2 = tid - 49152;
            int j = t2 & 7, lane = (t2 >> 3) & 63, c = (t2 >> 9) & 3,
                kk = (t2 >> 11) & 3, r = t2 >> 13;
            int k = kk * 32 + (lane >> 4) * 8 + j, n = c * 16 + (lane & 15);
            W1p[t2] = f2b(W1[(r * 128 + k) * 64 + n]);
        } else if (tid < 90112) {                // U0p [4][8][64][8]
            int t3 = tid - 73728;
            int j = t3 & 7, lane = (t3 >> 3) & 63, c = (t3 >> 9) & 7, kk = t3 >> 12;
            int k = kk * 32 + (lane >> 4) * 8 + j, n = c * 16 + (lane & 15);
            U0p[t3] = f2b(uW0[k * 128 + n]);
        } else if (tid < 98304) {                // U1p [4][4][64][8]
            int t4 = tid - 90112;
            int j = t4 & 7, lane = (t4 >> 3) & 63, c = (t4 >> 9) & 3, kk = t4 >> 11;
            int k = kk * 32 + (lane >> 4) * 8 + j, n = c * 16 + (lane & 15);
            U1p[t4] = f2b(uW1[k * 64 + n]);
        }
    } else {
        const int blk = blockIdx.x - 384;
        if (t < 3) sc[t] = 0;
        __syncthreads();
        int4 sv = ((const int4*)s)[blk * 256 + t];
        int l0 = 0, l1 = 0, l2 = 0, r;
        r = clmp3(sv.x); l0 += (r == 0); l1 += (r == 1); l2 += (r == 2);
        r = clmp3(sv.y); l0 += (r == 0); l1 += (r == 1); l2 += (r == 2);
        r = clmp3(sv.z); l0 += (r == 0); l1 += (r == 1); l2 += (r == 2);
        r = clmp3(sv.w); l0 += (r == 0); l1 += (r == 1); l2 += (r == 2);
        atomicAdd(&sc[0], l0); atomicAdd(&sc[1], l1); atomicAdd(&sc[2], l2);
        __syncthreads();
        if (t < 3) cntB[blk * 3 + t] = sc[t];
    }
}

// ---------------------------------------------------------------------------
// Kernel B = prep_ui (blocks 0..255, 512 thr) + passB scan/scatter
// (blocks 256..511, first 256 thr active, barriers by all).
// ---------------------------------------------------------------------------
__global__ __launch_bounds__(512) void kernelB(
    const float* __restrict__ u_emb, const float* __restrict__ i_emb,
    const u16t* __restrict__ U0p, const u16t* __restrict__ U1p,
    const float* __restrict__ uib0, const float* __restrict__ uib1,
    const int* __restrict__ s, const int* __restrict__ cntB,
    u16t* __restrict__ uiT, int* __restrict__ cntOut, int* __restrict__ rows)
{
    __shared__ __align__(16) u16t sA[32 * SAP];
    __shared__ __align__(16) u16t sH[32 * SAP];
    __shared__ int sTab[768];
    __shared__ int sBT[6];
    __shared__ int sS[256];
    const int t = threadIdx.x;

    if (blockIdx.x < 256) {
        // ---------------- prep_ui ----------------
        const int wave = t >> 6, lane = t & 63, m = lane & 15, kg = lane >> 4;
        const int c = wave, c2 = wave & 3, hlf = wave >> 2;
        const int B0 = blockIdx.x * 32;

        bf16x8 w0f[4], w1f[4];
#pragma unroll
        for (int kk = 0; kk < 4; ++kk) {
            w0f[kk] = *(const bf16x8*)(U0p + (((kk * 8 + c) * 64 + lane) << 3));
            w1f[kk] = *(const bf16x8*)(U1p + (((kk * 4 + c2) * 64 + lane) << 3));
        }
        const float b0 = uib0[c * 16 + m], b1 = uib1[c2 * 16 + m];

        {   // stage 32 rows of u||i (f32 -> bf16)
            const int row = t >> 4, seg = t & 15;
            const float* src = (seg < 8) ? (u_emb + (size_t)(B0 + row) * 64 + seg * 8)
                                         : (i_emb + (size_t)(B0 + row) * 64 + (seg - 8) * 8);
            float4 v0 = ((const float4*)src)[0], v1 = ((const float4*)src)[1];
            *(uint4*)&sA[row * SAP + seg * 8] = pack8(v0, v1);
        }
        __syncthreads();

#pragma unroll
        for (int mt = 0; mt < 2; ++mt) {
            const u16t* ap = &sA[(mt * 16 + m) * SAP + kg * 8];
            bf16x8 a0 = *(const bf16x8*)(ap),      a1 = *(const bf16x8*)(ap + 32);
            bf16x8 a2 = *(const bf16x8*)(ap + 64), a3 = *(const bf16x8*)(ap + 96);
            f32x4 acc = {0.f, 0.f, 0.f, 0.f};
            acc = __builtin_amdgcn_mfma_f32_16x16x32_bf16(a0, w0f[0], acc, 0, 0, 0);
            acc = __builtin_amdgcn_mfma_f32_16x16x32_bf16(a1, w0f[1], acc, 0, 0, 0);
            acc = __builtin_amdgcn_mfma_f32_16x16x32_bf16(a2, w0f[2], acc, 0, 0, 0);
            acc = __builtin_amdgcn_mfma_f32_16x16x32_bf16(a3, w0f[3], acc, 0, 0, 0);
#pragma unroll
            for (int j = 0; j < 4; ++j)
                sH[(mt * 16 + kg * 4 + j) * SAP + c * 16 + m] = f2b(lrelu(acc[j] + b0));
        }
        __syncthreads();

        {   // L1: wave (hlf,c2) handles tile mt=hlf
            const int mt = hlf;
            const u16t* hp = &sH[(mt * 16 + m) * SAP + kg * 8];
            bf16x8 a0 = *(const bf16x8*)(hp),      a1 = *(const bf16x8*)(hp + 32);
            bf16x8 a2 = *(const bf16x8*)(hp + 64), a3 = *(const bf16x8*)(hp + 96);
            f32x4 acc = {0.f, 0.f, 0.f, 0.f};
            acc = __builtin_amdgcn_mfma_f32_16x16x32_bf16(a0, w1f[0], acc, 0, 0, 0);
            acc = __builtin_amdgcn_mfma_f32_16x16x32_bf16(a1, w1f[1], acc, 0, 0, 0);
            acc = __builtin_amdgcn_mfma_f32_16x16x32_bf16(a2, w1f[2], acc, 0, 0, 0);
            acc = __builtin_amdgcn_mfma_f32_16x16x32_bf16(a3, w1f[3], acc, 0, 0, 0);
#pragma unroll
            for (int j = 0; j < 4; ++j)
                uiT[(size_t)(B0 + mt * 16 + kg * 4 + j) * 64 + c2 * 16 + m] =
                    f2b(lrelu(acc[j] + b1));
        }
    } else {
        // ---------------- passB ----------------
        const int blk = blockIdx.x - 256;
        if (t < 256) {
            sTab[t] = cntB[t]; sTab[t + 256] = cntB[t + 256]; sTab[t + 512] = cntB[t + 512];
        }
        __syncthreads();
        if (t < 3) {
            int base = 0, tot = 0;
            for (int b = 0; b < 256; ++b) {
                int v = sTab[b * 3 + t];
                if (b < blk) base += v;
                tot += v;
            }
            sBT[t] = base; sBT[3 + t] = tot;
        }
        int rr0 = 0, rr1 = 0, rr2 = 0, rr3 = 0, packed = 0;
        if (t < 256) {
            int4 sv = ((const int4*)s)[blk * 256 + t];
            rr0 = clmp3(sv.x); rr1 = clmp3(sv.y); rr2 = clmp3(sv.z); rr3 = clmp3(sv.w);
            packed = (1 << (11 * rr0)) + (1 << (11 * rr1))
                   + (1 << (11 * rr2)) + (1 << (11 * rr3));
            sS[t] = packed;
        }
        __syncthreads();
        for (int off = 1; off < 256; off <<= 1) {
            int v = 0;
            if (t >= off && t < 256) v = sS[t - off];
            __syncthreads();
            if (t < 256) sS[t] += v;
            __syncthreads();
        }
        if (t < 256) {
            const int excl = sS[t] - packed;
            const int g1 = sBT[3], g2 = sBT[3] + sBT[4];
            int rr[4] = { rr0, rr1, rr2, rr3 };
            int seen[3] = {0, 0, 0};
#pragma unroll
            for (int i = 0; i < 4; ++i) {
                int rl = rr[i];
                int gb = rl == 0 ? 0 : (rl == 1 ? g1 : g2);
                int pos = gb + sBT[rl] + ((excl >> (11 * rl)) & 2047) + seen[rl];
                seen[rl]++;
                rows[pos] = blk * 1024 + t * 4 + i;
            }
        }
        if (blk == 0 && t < 3) cntOut[t] = sBT[3 + t];
    }
}

// ---------------------------------------------------------------------------
// AO main v3: round-0 skeleton (2 sequential 64-row chunks/block) with the
// reduction rewritten off the LDS pipe:
//   - __shfl_xor (ds_swizzle) tree  -> DPP row_ror rotate-accumulate (VALU)
//   - LDS atomicAdd pred            -> one plain store per (row, c2) partial
//     into sPred4[64][4]; W phase sums 4 floats. No sPred zero-init.
// ---------------------------------------------------------------------------
__global__ __launch_bounds__(512, 4) void ao_main(
    const float* __restrict__ a_emb, const float* __restrict__ o_emb,
    const float* __restrict__ ao_b0, const float* __restrict__ ao_b1,
    const u16t* __restrict__ W0p, const u16t* __restrict__ W1p,
    const u16t* __restrict__ uiT, const int* __restrict__ rows,
    const int* __restrict__ tot, float* __restrict__ out)
{
    __shared__ __align__(16) u16t sA[64 * SAP];          // 17408 B
    __shared__ __align__(16) u16t sH[64 * SAP];          // 17408 B
    __shared__ __align__(16) u16t sUIl[64 * UIP];        //  9216 B
    __shared__ __align__(16) float sPred4[64][4];        //  1024 B

    const int n0 = tot[0], n1 = tot[1], n2 = tot[2];
    const int ch0 = (n0 + 63) >> 6, ch1 = (n1 + 63) >> 6, ch2 = (n2 + 63) >> 6;
    const int nch = ch0 + ch1 + ch2;

    const int t = threadIdx.x, wave = t >> 6, lane = t & 63, m = lane & 15, kg = lane >> 4;
    const int c = wave, c2 = wave & 3, hlf = wave >> 2;

    bf16x8 w0f[4], w1f[4];
    float b0 = 0.f, b1 = 0.f;
    int rprev = -1;

    for (int ci = 0; ci < 2; ++ci) {
        const int chunk = blockIdx.x * 2 + ci;
        if (chunk >= nch) break;                       // block-uniform
        int r, rel, bb, nb;
        if (chunk < ch0)            { r = 0; rel = chunk;             bb = 0;       nb = n0; }
        else if (chunk < ch0 + ch1) { r = 1; rel = chunk - ch0;       bb = n0;      nb = n1; }
        else                        { r = 2; rel = chunk - ch0 - ch1; bb = n0 + n1; nb = n2; }
        const int rstart = rel * 64;
        int nrows = nb - rstart; if (nrows > 64) nrows = 64;

        if (r != rprev) {            // block-uniform; taken once for most blocks
            const u16t* wp0 = W0p + r * 16384;
            const u16t* wp1 = W1p + r * 8192;
#pragma unroll
            for (int kk = 0; kk < 4; ++kk) {
                w0f[kk] = *(const bf16x8*)(wp0 + (((kk * 8 + c) * 64 + lane) << 3));
                w1f[kk] = *(const bf16x8*)(wp1 + (((kk * 4 + c2) * 64 + lane) << 3));
            }
            b0 = ao_b0[r * 128 + c * 16 + m];
            b1 = ao_b1[r * 64 + c2 * 16 + m];
            rprev = r;
        }

        // ---- S: gather rows (a||o f32 -> bf16) + ui rows ----
        {
            const int q = t >> 3, seg = t & 7;
            const int rid = rows[bb + rstart + (q < nrows ? q : nrows - 1)];
            const float* src = (seg < 4) ? (a_emb + (size_t)rid * 64 + seg * 16)
                                         : (o_emb + (size_t)rid * 64 + (seg - 4) * 16);
            float4 v0 = ((const float4*)src)[0], v1 = ((const float4*)src)[1];
            float4 v2 = ((const float4*)src)[2], v3 = ((const float4*)src)[3];
            uint4* dst = (uint4*)&sA[q * SAP + seg * 16];
            dst[0] = pack8(v0, v1);
            dst[1] = pack8(v2, v3);
            *(uint4*)&sUIl[q * UIP + seg * 8] =
                *(const uint4*)(uiT + ((size_t)(rid >> 5)) * 64 + seg * 8);  // b = rid/N
        }
        __syncthreads();

        // ---- L0 MFMA: h0 = lrelu(ao_in @ W0[r] + b0) -> sH ----
#pragma unroll
        for (int mt = 0; mt < 4; ++mt) {
            const u16t* ap = &sA[(mt * 16 + m) * SAP + kg * 8];
            bf16x8 a0 = *(const bf16x8*)(ap),      a1 = *(const bf16x8*)(ap + 32);
            bf16x8 a2 = *(const bf16x8*)(ap + 64), a3 = *(const bf16x8*)(ap + 96);
            f32x4 acc_a = {0.f, 0.f, 0.f, 0.f}, acc_b = {0.f, 0.f, 0.f, 0.f};
            acc_a = __builtin_amdgcn_mfma_f32_16x16x32_bf16(a0, w0f[0], acc_a, 0, 0, 0);
            acc_a = __builtin_amdgcn_mfma_f32_16x16x32_bf16(a1, w0f[1], acc_a, 0, 0, 0);
            acc_b = __builtin_amdgcn_mfma_f32_16x16x32_bf16(a2, w0f[2], acc_b, 0, 0, 0);
            acc_b = __builtin_amdgcn_mfma_f32_16x16x32_bf16(a3, w0f[3], acc_b, 0, 0, 0);
            f32x4 acc = acc_a + acc_b;
            unsigned pA = pk2(lrelu(acc[0] + b0), lrelu(acc[1] + b0));
            unsigned pB = pk2(lrelu(acc[2] + b0), lrelu(acc[3] + b0));
            u16t* hp = &sH[(mt * 16 + kg * 4) * SAP + c * 16 + m];
            hp[0]       = (u16t)pA;
            hp[SAP]     = (u16t)(pA >> 16);
            hp[2 * SAP] = (u16t)pB;
            hp[3 * SAP] = (u16t)(pB >> 16);
        }
        __syncthreads();

        // ---- L1 MFMA + bias + lrelu + dot(ui, h1); DPP-row reduce ----
        for (int mt = hlf; mt < 4; mt += 2) {
            const u16t* hp2 = &sH[(mt * 16 + m) * SAP + kg * 8];
            bf16x8 a0 = *(const bf16x8*)(hp2),      a1 = *(const bf16x8*)(hp2 + 32);
            bf16x8 a2 = *(const bf16x8*)(hp2 + 64), a3 = *(const bf16x8*)(hp2 + 96);
            f32x4 acc_a = {0.f, 0.f, 0.f, 0.f}, acc_b = {0.f, 0.f, 0.f, 0.f};
            acc_a = __builtin_amdgcn_mfma_f32_16x16x32_bf16(a0, w1f[0], acc_a, 0, 0, 0);
            acc_a = __builtin_amdgcn_mfma_f32_16x16x32_bf16(a1, w1f[1], acc_a, 0, 0, 0);
            acc_b = __builtin_amdgcn_mfma_f32_16x16x32_bf16(a2, w1f[2], acc_b, 0, 0, 0);
            acc_b = __builtin_amdgcn_mfma_f32_16x16x32_bf16(a3, w1f[3], acc_b, 0, 0, 0);
            f32x4 acc = acc_a + acc_b;
            const int o = c2 * 16 + m;
            float pj[4];
#pragma unroll
            for (int j = 0; j < 4; ++j) {
                const int rq = mt * 16 + kg * 4 + j;
                pj[j] = lrelu(acc[j] + b1) * b2f(sUIl[rq * UIP + o]);
            }
#pragma unroll
            for (int j = 0; j < 4; ++j) pj[j] = row16_sum(pj[j]);
            if (m < 4) {   // lane m stores pj[m]: one plain store per (row,c2)
                float v = m == 0 ? pj[0] : m == 1 ? pj[1] : m == 2 ? pj[2] : pj[3];
                sPred4[mt * 16 + kg * 4 + m][c2] = v;
            }
        }
        __syncthreads();

        // ---- W: sum 4 partials, scattered plain stores ----
        if (t < nrows) {
            const float4 v = *(const float4*)sPred4[t];
            out[rows[bb + rstart + t]] = (v.x + v.y) + (v.z + v.w);
        }
        // No barrier needed: next S writes sA/sUIl whose last reads are >=1
        // barrier back; sPred4[t] is read and later rewritten across 2 barriers.
    }
}

extern "C" void kernel_launch(void* const* d_in, const int* in_sizes, int n_in,
                              void* d_out, int out_size, void* d_ws, size_t ws_size,
                              hipStream_t stream) {
    (void)in_sizes; (void)n_in; (void)out_size; (void)ws_size;
    const float* u_emb = (const float*)d_in[0];
    const float* i_emb = (const float*)d_in[1];
    const float* a_emb = (const float*)d_in[2];
    const float* o_emb = (const float*)d_in[3];
    const int*   s     = (const int*)  d_in[4];
    const float* aoW0  = (const float*)d_in[5];
    const float* aob0  = (const float*)d_in[6];
    const float* aoW1  = (const float*)d_in[7];
    const float* aob1  = (const float*)d_in[8];
    const float* uiW0  = (const float*)d_in[9];
    const float* uib0  = (const float*)d_in[10];
    const float* uiW1  = (const float*)d_in[11];
    const float* uib1  = (const float*)d_in[12];
    float* out = (float*)d_out;

    char* ws = (char*)d_ws;
    u16t* W0p  = (u16t*)(ws);                 //  98304 B
    u16t* W1p  = (u16t*)(ws + 98304);         //  49152 B
    u16t* U0p  = (u16t*)(ws + 147456);        //  32768 B
    u16t* U1p  = (u16t*)(ws + 180224);        //  16384 B
    u16t* uiT  = (u16t*)(ws + 196608);        // 1048576 B (8192*64 bf16)
    int*  cntB = (int*) (ws + 1245184);       //   3072 B
    int*  totC = (int*) (ws + 1248256);       //     16 B
    int*  rowsP= (int*) (ws + 1248272);       // 1048576 B (262144 int)

    kernelA<<<dim3(640), dim3(256), 0, stream>>>(
        aoW0, aoW1, uiW0, uiW1, s, W0p, W1p, U0p, U1p, cntB);
    kernelB<<<dim3(512), dim3(512), 0, stream>>>(
        u_emb, i_emb, U0p, U1p, uib0, uib1, s, cntB, uiT, totC, rowsP);
    ao_main<<<dim3(2051), dim3(512), 0, stream>>>(
        a_emb, o_emb, aob0, aob1, W0p, W1p, uiT, rowsP, totC, out);
}